// Round 3
// baseline (570.035 us; speedup 1.0000x reference)
//
#include <hip/hip_runtime.h>

typedef unsigned short u16;
typedef __bf16 bf16_t;
typedef bf16_t bf16x8 __attribute__((ext_vector_type(8)));
typedef float f32x4 __attribute__((ext_vector_type(4)));
typedef float f32x16 __attribute__((ext_vector_type(16)));

#define LOG2E 1.4426950408889634f

__device__ __forceinline__ u16 f2bf(float f) {
  union { float f; unsigned u; } c; c.f = f;
  unsigned r = c.u + 0x7fffu + ((c.u >> 16) & 1u);
  return (u16)(r >> 16);
}
__device__ __forceinline__ float bf2f(u16 u) {
  union { unsigned u; float f; } c; c.u = ((unsigned)u) << 16;
  return c.f;
}

__device__ __forceinline__ void gload16(const void* g, void* l) {
  __builtin_amdgcn_global_load_lds(
      (const __attribute__((address_space(1))) unsigned int*)g,
      (__attribute__((address_space(3))) unsigned int*)l, 16, 0, 0);
}

__device__ __forceinline__ unsigned cvtpk(float lo, float hi) {
  unsigned r;
  asm("v_cvt_pk_bf16_f32 %0, %1, %2" : "=v"(r) : "v"(lo), "v"(hi));
  return r;
}
__device__ __forceinline__ void swap32(unsigned& a, unsigned& b) {
  asm("v_permlane32_swap_b32 %0, %1" : "+v"(a), "+v"(b));
}

#define MFMA16(a, b, c) __builtin_amdgcn_mfma_f32_16x16x32_bf16((a), (b), (c), 0, 0, 0)
#define MFMA32(a, b, c) __builtin_amdgcn_mfma_f32_32x32x16_bf16((a), (b), (c), 0, 0, 0)

// ---------------- prep kernels ----------------

__global__ __launch_bounds__(256) void k_convert_f32_bf16(const float* __restrict__ in,
                                                          u16* __restrict__ out, int n4) {
  int i = blockIdx.x * 256 + threadIdx.x;
  if (i >= n4) return;
  float4 v = ((const float4*)in)[i];
  ushort4 o;
  o.x = f2bf(v.x); o.y = f2bf(v.y); o.z = f2bf(v.z); o.w = f2bf(v.w);
  ((ushort4*)out)[i] = o;
}

// out[C][R] = bf16(in[R][C])
__global__ __launch_bounds__(256) void k_transpose_f32_bf16(const float* __restrict__ in,
                                                            u16* __restrict__ out, int R, int C) {
  __shared__ float tile[32][33];
  int tx = threadIdx.x, ty = threadIdx.y;
  int bx = blockIdx.x * 32, by = blockIdx.y * 32;
#pragma unroll
  for (int i = 0; i < 4; i++)
    tile[ty + i * 8][tx] = in[(size_t)(by + ty + i * 8) * C + bx + tx];
  __syncthreads();
#pragma unroll
  for (int i = 0; i < 4; i++)
    out[(size_t)(bx + ty + i * 8) * R + by + tx] = f2bf(tile[tx][ty + i * 8]);
}

__global__ __launch_bounds__(256) void k_transpose_bf16(const u16* __restrict__ in,
                                                        u16* __restrict__ out, int R, int C) {
  __shared__ u16 tile[32][33];
  int tx = threadIdx.x, ty = threadIdx.y;
  int bx = blockIdx.x * 32, by = blockIdx.y * 32;
#pragma unroll
  for (int i = 0; i < 4; i++)
    tile[ty + i * 8][tx] = in[(size_t)(by + ty + i * 8) * C + bx + tx];
  __syncthreads();
#pragma unroll
  for (int i = 0; i < 4; i++)
    out[(size_t)(bx + ty + i * 8) * R + by + tx] = tile[tx][ty + i * 8];
}

// ---------------- RoPE (in place, bf16) ----------------
__global__ __launch_bounds__(256) void k_rope(u16* __restrict__ x, const int* __restrict__ pos,
                                              int nh_mask, int nh_shift, int width) {
  int idx = blockIdx.x * 256 + threadIdx.x;
  int i = idx & 127;
  int h = (idx >> 7) & nh_mask;
  int row = idx >> (7 + nh_shift);
  int p = pos[row];
  float f = (float)p * exp2f((float)i * (-13.287712379549449f / 128.f));
  float sn, cs;
  sincosf(f, &sn, &cs);
  size_t base = (size_t)row * width + h * 256 + i;
  float x1 = bf2f(x[base]), x2 = bf2f(x[base + 128]);
  x[base] = f2bf(x1 * cs - x2 * sn);
  x[base + 128] = f2bf(x2 * cs + x1 * sn);
}

// ---------------- GEMM: C[M][N] = A[M][K] * Bt[N][K]^T  (m97-style) ----------------

template <int OUT_BF16>
__global__ __launch_bounds__(256) void k_gemm_bt(const u16* __restrict__ A,
                                                 const u16* __restrict__ Bt,
                                                 void* __restrict__ C, int M, int N, int K) {
  __shared__ u16 As[128 * 64];
  __shared__ u16 Bs[128 * 64];
  const int tid = threadIdx.x;
  const int lane = tid & 63;
  const int w = tid >> 6;
  const int l15 = lane & 15, l4 = lane >> 4;
  const int wr = w >> 1, wc = w & 1;
  const int bx = blockIdx.x, by = blockIdx.y;

  f32x4 acc[4][4];
#pragma unroll
  for (int a = 0; a < 4; a++)
#pragma unroll
    for (int b2 = 0; b2 < 4; b2++) acc[a][b2] = (f32x4){0.f, 0.f, 0.f, 0.f};

  const u16* Abase = A + (size_t)by * 128 * K;
  const u16* Bbase = Bt + (size_t)bx * 128 * K;

  for (int kk = 0; kk < K; kk += 64) {
    __syncthreads();
#pragma unroll
    for (int j = 0; j < 4; j++) {
      int ci = w * 256 + j * 64 + lane;
      int row = ci >> 3, c = ci & 7;
      gload16(Abase + (size_t)row * K + kk + c * 8, (char*)As + ci * 16);
      gload16(Bbase + (size_t)row * K + kk + c * 8, (char*)Bs + ci * 16);
    }
    __syncthreads();
#pragma unroll
    for (int kc = 0; kc < 2; kc++) {
      int kb = kc * 64 + l4 * 16;
      bf16x8 av[4], bv[4];
#pragma unroll
      for (int mt = 0; mt < 4; mt++)
        av[mt] = *(const bf16x8*)((const char*)As + (wr * 64 + mt * 16 + l15) * 128 + kb);
#pragma unroll
      for (int nt = 0; nt < 4; nt++)
        bv[nt] = *(const bf16x8*)((const char*)Bs + (wc * 64 + nt * 16 + l15) * 128 + kb);
#pragma unroll
      for (int mt = 0; mt < 4; mt++)
#pragma unroll
        for (int nt = 0; nt < 4; nt++) acc[mt][nt] = MFMA16(av[mt], bv[nt], acc[mt][nt]);
    }
  }
#pragma unroll
  for (int mt = 0; mt < 4; mt++) {
#pragma unroll
    for (int nt = 0; nt < 4; nt++) {
      int col = bx * 128 + wc * 64 + nt * 16 + l15;
#pragma unroll
      for (int r = 0; r < 4; r++) {
        int row = by * 128 + wr * 64 + mt * 16 + l4 * 4 + r;
        if (OUT_BF16)
          ((u16*)C)[(size_t)row * N + col] = f2bf(acc[mt][nt][r]);
        else
          ((float*)C)[(size_t)row * N + col] = acc[mt][nt][r];
      }
    }
  }
}

// ---------------- flash attention (32x32 MFMA, swapped QK^T, in-reg softmax) ----------------
// 256 threads (4 waves), QBLK=128 (32 q-rows/wave), KVBLK=32, double-buffered K/V.
// LDS: K [32][256]*2 + V [256][32]*2 = 64 KB -> 2 blocks/CU.
// grid (16, 32); qb reversed so heavy blocks launch first.
__global__ __launch_bounds__(256, 2) void k_attn(const u16* __restrict__ Q,
                                                 const u16* __restrict__ Kb,
                                                 const u16* __restrict__ Vt,
                                                 u16* __restrict__ AO) {
  extern __shared__ char smem[];
  char* Kc = smem;
  char* Kn = smem + 16384;
  char* Vc = smem + 32768;
  char* Vn = smem + 49152;

  const int tid = threadIdx.x, lane = tid & 63, w = tid >> 6;
  const int r31 = lane & 31, hi = lane >> 5;
  const int qb = (int)gridDim.x - 1 - (int)blockIdx.x;
  const int bh = blockIdx.y;
  const int b = bh >> 4, h = bh & 15, kv = h >> 2;

  // Q fragments (B-operand): lane holds q-row r31, k-range kc*16 + hi*8
  bf16x8 qreg[16];
  {
    const u16* qp = Q + (size_t)(b * 2048 + qb * 128 + w * 32 + r31) * 4096 + h * 256 + hi * 8;
#pragma unroll
    for (int kc = 0; kc < 16; kc++) qreg[kc] = *(const bf16x8*)(qp + kc * 16);
  }

  f32x16 o[8];
#pragma unroll
  for (int df = 0; df < 8; df++)
#pragma unroll
    for (int j = 0; j < 16; j++) o[df][j] = 0.f;
  float mrow = -3e38f, lrow = 0.f;

  const int tmax = 4 * qb + 3;
  const int tlim = 4 * qb + w;  // wave active while t <= tlim; t == tlim is diagonal
  const int qloc = qb * 128 + w * 32 + r31;
  const int col0b = b * 2048;

  auto STAGE = [&](int t, char* Kd, char* Vd) {
    int col0 = col0b + t * 32;
#pragma unroll
    for (int j = 0; j < 4; j++) {
      int ci = j * 256 + tid;
      int row = ci >> 5, c = ci & 31;
      int cg = (c & 24) | ((c ^ row) & 7);
      gload16(Kb + (size_t)(col0 + row) * 1024 + kv * 256 + cg * 8, Kd + ci * 16);
    }
#pragma unroll
    for (int j = 0; j < 4; j++) {
      int ci = j * 256 + tid;
      int row = ci >> 2, c = ci & 3;
      int g = (c - (row >> 1)) & 3;
      gload16(Vt + (size_t)(kv * 256 + row) * 4096 + col0 + g * 8, Vd + ci * 16);
    }
  };

  STAGE(0, Kc, Vc);
  __syncthreads();

  for (int t = 0; t <= tmax; ++t) {
    if (t < tmax) STAGE(t + 1, Kn, Vn);

    if (t <= tlim) {
      // ---- QK^T swapped: S[kv][q] = mfma(K, Q); lane holds q-col r31, 16 kv rows ----
      f32x16 sa;
#pragma unroll
      for (int j = 0; j < 16; j++) sa[j] = 0.f;
#pragma unroll
      for (int kc = 0; kc < 16; kc++) {
        int ch = kc * 2 + hi;
        int cs = (ch & 24) | ((ch ^ r31) & 7);
        bf16x8 kf = *(const bf16x8*)(Kc + r31 * 512 + cs * 16);
        sa = MFMA32(kf, qreg[kc], sa);
      }

      // ---- scale (+mask on diagonal) in log2 domain ----
      const float C = 0.0625f * LOG2E;
      float z[16];
#pragma unroll
      for (int j = 0; j < 16; j++) z[j] = sa[j] * C;
      if (t == tlim) {
#pragma unroll
        for (int j = 0; j < 16; j++) {
          int kvg = t * 32 + (j & 3) + 8 * (j >> 2) + 4 * hi;
          if (kvg > qloc) z[j] = -1e30f;
        }
      }

      // ---- in-register softmax with defer-max ----
      float m0 = z[0];
#pragma unroll
      for (int j = 1; j < 16; j++) m0 = fmaxf(m0, z[j]);
      m0 = fmaxf(m0, __shfl_xor(m0, 32));
      if (__any(m0 > mrow + 11.54f)) {  // rare after first tile
        float mn = fmaxf(mrow, m0);
        float alpha = exp2f(mrow - mn);
        mrow = mn;
        lrow *= alpha;
        float af[16];
#pragma unroll
        for (int j = 0; j < 16; j++) af[j] = __shfl(alpha, (j & 3) + 8 * (j >> 2) + 4 * hi);
#pragma unroll
        for (int df = 0; df < 8; df++)
#pragma unroll
          for (int j = 0; j < 16; j++) o[df][j] *= af[j];
      }
      float pf[16];
      float sum = 0.f;
#pragma unroll
      for (int j = 0; j < 16; j++) {
        pf[j] = exp2f(z[j] - mrow);
        sum += pf[j];
      }
      sum += __shfl_xor(sum, 32);
      lrow += sum;

      // ---- pack P -> A-fragments (cvt_pk + permlane32_swap) ----
      unsigned a0 = cvtpk(pf[0], pf[1]), a2 = cvtpk(pf[4], pf[5]);
      swap32(a0, a2);
      unsigned a1 = cvtpk(pf[2], pf[3]), a3 = cvtpk(pf[6], pf[7]);
      swap32(a1, a3);
      unsigned b0 = cvtpk(pf[8], pf[9]), b2 = cvtpk(pf[12], pf[13]);
      swap32(b0, b2);
      unsigned b1 = cvtpk(pf[10], pf[11]), b3 = cvtpk(pf[14], pf[15]);
      swap32(b1, b3);
      union UU { unsigned u[4]; bf16x8 v; };
      UU ua; ua.u[0] = a0; ua.u[1] = a1; ua.u[2] = a2; ua.u[3] = a3;
      UU ub; ub.u[0] = b0; ub.u[1] = b1; ub.u[2] = b2; ub.u[3] = b3;
      bf16x8 pa0 = ua.v, pa1 = ub.v;

      // ---- PV: O[q][d] += P * V ----
#pragma unroll
      for (int df = 0; df < 8; df++) {
        int vr = df * 32 + r31;
        int c0 = (hi + (vr >> 1)) & 3;
        int c1 = (2 + hi + (vr >> 1)) & 3;
        bf16x8 v0 = *(const bf16x8*)(Vc + vr * 64 + c0 * 16);
        bf16x8 v1 = *(const bf16x8*)(Vc + vr * 64 + c1 * 16);
        o[df] = MFMA32(pa0, v0, o[df]);
        o[df] = MFMA32(pa1, v1, o[df]);
      }
    }

    __syncthreads();  // drains prefetch; all reads of cur done
    char* tk = Kc; Kc = Kn; Kn = tk;
    char* tv = Vc; Vc = Vn; Vn = tv;
  }

  // ---- epilogue: broadcast 1/l to o-row layout, store ----
  float rl = 1.f / lrow;
  float rf[16];
#pragma unroll
  for (int j = 0; j < 16; j++) rf[j] = __shfl(rl, (j & 3) + 8 * (j >> 2) + 4 * hi);
  size_t rowbase = (size_t)(b * 2048 + qb * 128 + w * 32);
#pragma unroll
  for (int df = 0; df < 8; df++)
#pragma unroll
    for (int j = 0; j < 16; j++) {
      int qr = (j & 3) + 8 * (j >> 2) + 4 * hi;
      AO[(rowbase + qr) * 4096 + h * 256 + df * 32 + r31] = f2bf(o[df][j] * rf[j]);
    }
}

// ---------------- host ----------------

// ws layout (bytes). AO aliases Xb+Wqt (dead by then). Needs 112 MB of ws.
#define OFF_XB   0u
#define OFF_WQT  16777216u
#define OFF_WKT  33554432u
#define OFF_WVT  37748736u
#define OFF_WOT  41943040u
#define OFF_QB   58720256u
#define OFF_KB   92274688u
#define OFF_VB   100663296u
#define OFF_VT   109051904u
#define OFF_AO   0u

extern "C" void kernel_launch(void* const* d_in, const int* in_sizes, int n_in,
                              void* d_out, int out_size, void* d_ws, size_t ws_size,
                              hipStream_t stream) {
  const float* hs = (const float*)d_in[0];
  const int* pos = (const int*)d_in[1];
  const float* wq = (const float*)d_in[2];
  const float* wk = (const float*)d_in[3];
  const float* wv = (const float*)d_in[4];
  const float* wo = (const float*)d_in[5];
  float* out = (float*)d_out;
  char* ws = (char*)d_ws;

  u16* Xb  = (u16*)(ws + OFF_XB);
  u16* Wqt = (u16*)(ws + OFF_WQT);
  u16* Wkt = (u16*)(ws + OFF_WKT);
  u16* Wvt = (u16*)(ws + OFF_WVT);
  u16* Wot = (u16*)(ws + OFF_WOT);
  u16* Qb  = (u16*)(ws + OFF_QB);
  u16* Kb  = (u16*)(ws + OFF_KB);
  u16* Vb  = (u16*)(ws + OFF_VB);
  u16* Vt  = (u16*)(ws + OFF_VT);
  u16* AO  = (u16*)(ws + OFF_AO);

  dim3 tb(32, 8);

  // prep: convert + transposes
  k_convert_f32_bf16<<<8192, 256, 0, stream>>>(hs, Xb, 2097152);
  k_transpose_f32_bf16<<<dim3(128, 64), tb, 0, stream>>>(wq, Wqt, 2048, 4096);
  k_transpose_f32_bf16<<<dim3(32, 64), tb, 0, stream>>>(wk, Wkt, 2048, 1024);
  k_transpose_f32_bf16<<<dim3(32, 64), tb, 0, stream>>>(wv, Wvt, 2048, 1024);
  k_transpose_f32_bf16<<<dim3(64, 128), tb, 0, stream>>>(wo, Wot, 4096, 2048);

  // QKV projections
  k_gemm_bt<1><<<dim3(32, 32), 256, 0, stream>>>(Xb, Wqt, Qb, 4096, 4096, 2048);
  k_gemm_bt<1><<<dim3(8, 32), 256, 0, stream>>>(Xb, Wkt, Kb, 4096, 1024, 2048);
  k_gemm_bt<1><<<dim3(8, 32), 256, 0, stream>>>(Xb, Wvt, Vb, 4096, 1024, 2048);

  // RoPE on Q and K
  k_rope<<<32768, 256, 0, stream>>>(Qb, pos, 15, 4, 4096);
  k_rope<<<8192, 256, 0, stream>>>(Kb, pos, 3, 2, 1024);

  // V^T for attention PV operand
  k_transpose_bf16<<<dim3(32, 128), tb, 0, stream>>>(Vb, Vt, 4096, 1024);

  // flash attention: 256 threads, 64 KB dynamic LDS, 2 blocks/CU
  (void)hipFuncSetAttribute((const void*)k_attn, hipFuncAttributeMaxDynamicSharedMemorySize, 65536);
  k_attn<<<dim3(16, 32), 256, 65536, stream>>>(Qb, Kb, Vt, AO);

  // output projection (fp32 out)
  k_gemm_bt<0><<<dim3(16, 32), 256, 0, stream>>>(AO, Wot, out, 4096, 2048, 4096);
}